// Round 6
// baseline (385.514 us; speedup 1.0000x reference)
//
#include <hip/hip_runtime.h>

// GCN: 3x GCNConv(sym-norm, self-loops) + ReLU, mean-pool per graph, FC.
// Strategy: fold dinv into per-layer G = dinv .* (X@W); build dst-CSR once
// per call so aggregation is atomic-free.
// R1-R7: store-coalescing chase falsified. R8: zero global atomics in CSR
//   build. R10: G fp16 (1 line/edge). R13 -> 405us. R14 fused aggmm -> 376us.
// R15/16: XCD feature-split FALSIFIED (32B requests: request-rate doubled).
// R17: pipelined gather -> 358.7us; agg 48us, VALUBusy 44%.
// R18: 2-pass src-split FALSIFIED as run (streaming thrash + extra traffic).
// R19: 4 lanes x 16B gather: 4x fewer instrs, VALU 17%, occ 28%, SAME 48us
//   -> agg limited by per-CU outstanding-request cap (~60) x avg latency
//   (~550cy @ ~50% L2 hit). Only remaining lever: LATENCY via residency
//   with 64B requests kept.
// R20: XCD node-partitioned gather. Rows pre-split by src (mid[] from
//   k_place, verified R18). One kernel, 2x grid: b%8<4 -> low segments
//   (gather G rows <50K = 3.2MB), b%8>=4 -> high. Per-XCD gather WS fits
//   4MB L2 for the whole kernel. Halves write fp32 partials PA/PB (NT);
//   streaming merge kernel sums + dinv/bias/relu + fused 32x32 GEMM.
//   Predict agghalf 20-26us (FETCH 20-30MB), ~30us/layer, total ~305us.
//   Falsifier: agghalf >= 40us => chip-level request-rate cap, agg floor.

#include <hip/hip_fp16.h>

#define NN 100000
#define HALFN 50000
#define EE 3200000
#define FIN 128
#define HID 32
#define NGR 256
#define NC 10
#define NBUK 256
#define BRANGE 391    // 256*391 = 100096 >= NN
#define BSLACK 13400  // mean 12500, sd ~112 -> ~8 sigma slack (input is fixed)
#define TILE 8192
#define NGRP ((NN + 63) / 64)               // 1563 node-groups of 64
#define AGH_GRID (8 * ((NGRP + 3) / 4))     // 3128: b%8 -> XCD, half = (b&7)>>2

typedef _Float16 h4 __attribute__((ext_vector_type(4)));
typedef _Float16 h8 __attribute__((ext_vector_type(8)));
typedef float f4 __attribute__((ext_vector_type(4)));
typedef int i4u __attribute__((ext_vector_type(4), aligned(4)));

#define NTL(p) __builtin_nontemporal_load(p)
#define NTL4(p) __builtin_nontemporal_load(reinterpret_cast<const i4u*>(p))

__global__ void k_init(int* __restrict__ bcur) {
  int t = threadIdx.x;
  if (t < NBUK) bcur[t] = t * BSLACK;
}

// Pass A: LDS multisplit of one 8192-edge tile into 256 dst-buckets.
__global__ __launch_bounds__(1024) void k_bucket(const int* __restrict__ ei,
                                                 int* __restrict__ bcur,
                                                 long long* __restrict__ bpair) {
  __shared__ int hist[NBUK];
  __shared__ int bexc[NBUK];
  __shared__ int cnt[NBUK];
  __shared__ int gofs[NBUK];
  __shared__ long long sorted[TILE];  // 64 KB
  int t = threadIdx.x;
  const int* src = ei;
  const int* dst = ei + EE;
  int e0 = blockIdx.x * TILE;
  int tn = EE - e0;
  if (tn > TILE) tn = TILE;

  if (t < NBUK) { hist[t] = 0; cnt[t] = 0; }
  __syncthreads();

  for (int i = t; i < tn; i += 1024) {
    int d = __builtin_nontemporal_load(&dst[e0 + i]);
    atomicAdd(&hist[d / BRANGE], 1);
  }
  __syncthreads();

  int hv = 0;
  if (t < NBUK) { hv = hist[t]; bexc[t] = hv; }
  __syncthreads();
#pragma unroll
  for (int off = 1; off < NBUK; off <<= 1) {
    int x = 0;
    if (t < NBUK && t >= off) x = bexc[t - off];
    __syncthreads();
    if (t < NBUK) bexc[t] += x;
    __syncthreads();
  }
  if (t < NBUK) {
    int inc = bexc[t];
    bexc[t] = inc - hv;
    if (hv > 0) gofs[t] = atomicAdd(&bcur[t], hv);  // ~65K atomics total
  }
  __syncthreads();

  for (int i = t; i < tn; i += 1024) {
    int d = dst[e0 + i];
    int s = src[e0 + i];
    int q = d / BRANGE;
    int p = bexc[q] + atomicAdd(&cnt[q], 1);
    sorted[p] = ((long long)(unsigned)d << 32) | (unsigned)s;
  }
  __syncthreads();

  for (int i = t; i < tn; i += 1024) {
    long long pr = sorted[i];
    int q = (int)(unsigned)(pr >> 32) / BRANGE;
    __builtin_nontemporal_store(pr, &bpair[(size_t)gofs[q] + (i - bexc[q])]);
  }
}

// Fused CSR finalize: one 1024-thread block per bucket, zero global atomics.
// Rows segmented [src<HALFN | src>=HALFN]; mid[n] = split point (R18-verified).
__global__ __launch_bounds__(1024) void k_place(const long long* __restrict__ bpair,
                                                const int* __restrict__ bcur,
                                                float* __restrict__ dinv,
                                                int* __restrict__ row_ptr,
                                                int* __restrict__ mid,
                                                int* __restrict__ col) {
  __shared__ int bs[NBUK];
  __shared__ int cnt[BRANGE];   // total per dst; becomes cursor A
  __shared__ int cntA[BRANGE];  // src<HALFN per dst; becomes cursor B
  __shared__ int sc[1024];
  int b = blockIdx.x, t = threadIdx.x;

  if (t < NBUK) bs[t] = bcur[t] - t * BSLACK;
  __syncthreads();
#pragma unroll
  for (int off = 1; off < NBUK; off <<= 1) {
    int x = 0;
    if (t < NBUK && t >= off) x = bs[t - off];
    __syncthreads();
    if (t < NBUK) bs[t] += x;
    __syncthreads();
  }
  __syncthreads();
  int sz = bcur[b] - b * BSLACK;
  int colbase = bs[b] - sz;

  if (t < BRANGE) { cnt[t] = 0; cntA[t] = 0; }
  __syncthreads();

  int lo = b * BRANGE;
  int nnode = NN - lo;
  if (nnode > BRANGE) nnode = BRANGE;
  size_t e0 = (size_t)b * BSLACK;

  for (int i = t; i < sz; i += 1024) {
    long long pr = bpair[e0 + i];
    int d = (int)(unsigned)(pr >> 32);
    int s = (int)(unsigned)(pr & 0xffffffffLL);
    atomicAdd(&cnt[d - lo], 1);
    if (s < HALFN) atomicAdd(&cntA[d - lo], 1);
  }
  __syncthreads();

  int v = (t < BRANGE) ? cnt[t] : 0;
  sc[t] = v;
  __syncthreads();
#pragma unroll
  for (int off = 1; off < 1024; off <<= 1) {
    int x = (t >= off) ? sc[t - off] : 0;
    __syncthreads();
    sc[t] += x;
    __syncthreads();
  }
  int excl = sc[t] - v;
  if (t < nnode) {
    row_ptr[lo + t] = colbase + excl;
    dinv[lo + t] = rsqrtf((float)(v + 1));  // +1 = self-loop
  }
  if (t < BRANGE) {
    int ca = cntA[t];
    cnt[t] = colbase + excl;            // cursor A (lower-half segment)
    cntA[t] = colbase + excl + ca;      // cursor B (upper-half segment)
    if (t < nnode) mid[lo + t] = colbase + excl + ca;
  }
  if (b == NBUK - 1 && t == 0) row_ptr[NN] = EE;
  __syncthreads();

  for (int i = t; i < sz; i += 1024) {
    long long pr = bpair[e0 + i];
    int d = (int)(unsigned)(pr >> 32);
    int s = (int)(unsigned)(pr & 0xffffffffLL);
    int* cptr = (s < HALFN) ? &cnt[d - lo] : &cntA[d - lo];
    int pos = atomicAdd(cptr, 1);
    col[pos] = s;
  }
}

// G = dinv .* (X @ W), stored fp16 [node][32] (64B rows = 1 cache line).
template <int K>
__global__ __launch_bounds__(256) void k_gemm(const float* __restrict__ X,
                                              const float* __restrict__ W,
                                              const float* __restrict__ dinv,
                                              _Float16* __restrict__ Gout) {
  __shared__ float Wl[K * HID];
  __shared__ float xs[128 * 36];
  int t = threadIdx.x;
  for (int i = t; i < K * HID; i += 256) Wl[i] = W[i];
  int node0 = blockIdx.x * 128;
  int ng = t >> 3, f4i = t & 7;
  float acc[4][4];
#pragma unroll
  for (int j = 0; j < 4; j++)
#pragma unroll
    for (int c = 0; c < 4; c++) acc[j][c] = 0.f;

  for (int kc = 0; kc < K; kc += 32) {
    __syncthreads();
#pragma unroll
    for (int j = 0; j < 4; j++) {
      int idx = t + 256 * j;
      int r = idx >> 3, c4 = idx & 7;
      int row = node0 + r;
      if (row >= NN) row = NN - 1;
      float4 v = *reinterpret_cast<const float4*>(&X[(size_t)row * K + kc + c4 * 4]);
      *reinterpret_cast<float4*>(&xs[r * 36 + c4 * 4]) = v;
    }
    __syncthreads();
#pragma unroll
    for (int k4 = 0; k4 < 8; k4++) {
      float4 xv[4];
#pragma unroll
      for (int j = 0; j < 4; j++)
        xv[j] = *reinterpret_cast<const float4*>(&xs[(ng * 4 + j) * 36 + k4 * 4]);
#pragma unroll
      for (int kk = 0; kk < 4; kk++) {
        float4 wv = *reinterpret_cast<const float4*>(&Wl[(kc + k4 * 4 + kk) * HID + f4i * 4]);
#pragma unroll
        for (int j = 0; j < 4; j++) {
          float xvj = (kk == 0) ? xv[j].x : (kk == 1) ? xv[j].y : (kk == 2) ? xv[j].z : xv[j].w;
          acc[j][0] += xvj * wv.x;
          acc[j][1] += xvj * wv.y;
          acc[j][2] += xvj * wv.z;
          acc[j][3] += xvj * wv.w;
        }
      }
    }
  }
#pragma unroll
  for (int j = 0; j < 4; j++) {
    int node = node0 + ng * 4 + j;
    if (node < NN) {
      float s = dinv[node];
      h4 o;
      o.x = (_Float16)(acc[j][0] * s);
      o.y = (_Float16)(acc[j][1] * s);
      o.z = (_Float16)(acc[j][2] * s);
      o.w = (_Float16)(acc[j][3] * s);
      reinterpret_cast<h4*>(Gout)[(size_t)node * 8 + f4i] = o;
    }
  }
}

// R19 gather core: 4 lanes/node, h8 (16B) loads, chunk 8 in flight,
// col prefetch one chunk ahead, masked full-width tail.
#define GATH8_DECL                                                         \
  h8 v0 = G8[(size_t)ca.x * 4 + l], v1 = G8[(size_t)ca.y * 4 + l],         \
     v2 = G8[(size_t)ca.z * 4 + l], v3 = G8[(size_t)ca.w * 4 + l],         \
     v4 = G8[(size_t)cb.x * 4 + l], v5 = G8[(size_t)cb.y * 4 + l],         \
     v6 = G8[(size_t)cb.z * 4 + l], v7 = G8[(size_t)cb.w * 4 + l];

#define ACC8                                                               \
  _Pragma("unroll") for (int f = 0; f < 8; f++) {                          \
    accA[f] += (float)v0[f];                                               \
    accB[f] += (float)v1[f];                                               \
    accA[f] += (float)v2[f];                                               \
    accB[f] += (float)v3[f];                                               \
    accA[f] += (float)v4[f];                                               \
    accB[f] += (float)v5[f];                                               \
    accA[f] += (float)v6[f];                                               \
    accB[f] += (float)v7[f];                                               \
  }

#define AGG_GATHER_LOOP                                                    \
  int i = beg;                                                             \
  int nch = (end - beg) >> 3;                                              \
  if (nch > 0) {                                                           \
    i4u ca = NTL4(&col[i]);                                                \
    i4u cb = NTL4(&col[i + 4]);                                            \
    i += 8;                                                                \
    for (int k = 1; k < nch; k++) {                                        \
      GATH8_DECL;                                                          \
      i4u na = NTL4(&col[i]);                                              \
      i4u nb = NTL4(&col[i + 4]);                                          \
      i += 8;                                                              \
      ACC8;                                                                \
      ca = na; cb = nb;                                                    \
    }                                                                      \
    { GATH8_DECL; ACC8; }                                                  \
  }                                                                        \
  int rem = end - i;                                                       \
  if (rem > 0) {                                                           \
    int e1 = end - 1;                                                      \
    int j1 = (i + 1 > e1) ? e1 : i + 1;                                    \
    int j2 = (i + 2 > e1) ? e1 : i + 2;                                    \
    int j3 = (i + 3 > e1) ? e1 : i + 3;                                    \
    int j4 = (i + 4 > e1) ? e1 : i + 4;                                    \
    int j5 = (i + 5 > e1) ? e1 : i + 5;                                    \
    int j6 = (i + 6 > e1) ? e1 : i + 6;                                    \
    int j7 = (i + 7 > e1) ? e1 : i + 7;                                    \
    int c0 = NTL(&col[i]), c1 = NTL(&col[j1]), c2 = NTL(&col[j2]),         \
        c3 = NTL(&col[j3]), c4 = NTL(&col[j4]), c5 = NTL(&col[j5]),        \
        c6 = NTL(&col[j6]), c7 = NTL(&col[j7]);                            \
    h8 w0 = G8[(size_t)c0 * 4 + l], w1 = G8[(size_t)c1 * 4 + l],           \
       w2 = G8[(size_t)c2 * 4 + l], w3 = G8[(size_t)c3 * 4 + l],           \
       w4 = G8[(size_t)c4 * 4 + l], w5 = G8[(size_t)c5 * 4 + l],           \
       w6 = G8[(size_t)c6 * 4 + l], w7 = G8[(size_t)c7 * 4 + l];           \
    float m;                                                               \
    _Pragma("unroll") for (int f = 0; f < 8; f++) accA[f] += (float)w0[f]; \
    m = (1 < rem) ? 1.f : 0.f;                                             \
    _Pragma("unroll") for (int f = 0; f < 8; f++) accB[f] = fmaf(m, (float)w1[f], accB[f]); \
    m = (2 < rem) ? 1.f : 0.f;                                             \
    _Pragma("unroll") for (int f = 0; f < 8; f++) accA[f] = fmaf(m, (float)w2[f], accA[f]); \
    m = (3 < rem) ? 1.f : 0.f;                                             \
    _Pragma("unroll") for (int f = 0; f < 8; f++) accB[f] = fmaf(m, (float)w3[f], accB[f]); \
    m = (4 < rem) ? 1.f : 0.f;                                             \
    _Pragma("unroll") for (int f = 0; f < 8; f++) accA[f] = fmaf(m, (float)w4[f], accA[f]); \
    m = (5 < rem) ? 1.f : 0.f;                                             \
    _Pragma("unroll") for (int f = 0; f < 8; f++) accB[f] = fmaf(m, (float)w5[f], accB[f]); \
    m = (6 < rem) ? 1.f : 0.f;                                             \
    _Pragma("unroll") for (int f = 0; f < 8; f++) accA[f] = fmaf(m, (float)w6[f], accA[f]); \
    m = (7 < rem) ? 1.f : 0.f;                                             \
    _Pragma("unroll") for (int f = 0; f < 8; f++) accB[f] = fmaf(m, (float)w7[f], accB[f]); \
  }                                                                        \
  _Pragma("unroll") for (int f = 0; f < 8; f++) accA[f] += accB[f];

// XCD node-partitioned half-aggregation. b%8 -> XCD round-robin:
// XCDs 0-3 (half 0) gather only G rows < HALFN (3.2MB, L2-resident);
// XCDs 4-7 (half 1) only rows >= HALFN. Self-loop term goes to the half
// owning node n. Raw fp32 partial (no dinv/bias) -> PA/PB, NT stores.
__global__ __launch_bounds__(256) void k_agghalf(const _Float16* __restrict__ Gin,
                                                 const int* __restrict__ col,
                                                 const int* __restrict__ row_ptr,
                                                 const int* __restrict__ mid,
                                                 float* __restrict__ Pbuf) {
  const h8* G8 = reinterpret_cast<const h8*>(Gin);
  int b = blockIdx.x;
  int g8 = b & 7;
  int half = g8 >> 2;
  int idx = (b >> 3) * 4 + (g8 & 3);
  if (idx >= NGRP) return;
  int t = threadIdx.x;
  int l = t & 3;
  int slot = t >> 2;
  int n = idx * 64 + slot;
  int nl = (n < NN) ? n : NN - 1;

  int beg, end;
  if (half == 0) { beg = row_ptr[nl]; end = mid[nl]; }
  else           { beg = mid[nl];     end = row_ptr[nl + 1]; }

  float accA[8], accB[8];
#pragma unroll
  for (int f = 0; f < 8; f++) { accA[f] = 0.f; accB[f] = 0.f; }
  // Self-loop term: owned by the half whose G-range contains n.
  if ((nl < HALFN) == (half == 0)) {
    h8 g0 = G8[(size_t)nl * 4 + l];
#pragma unroll
    for (int f = 0; f < 8; f++) accA[f] = (float)g0[f];
  }

  AGG_GATHER_LOOP;

  if (n < NN) {
    float* P = Pbuf + (size_t)half * ((size_t)NN * HID);
    f4 o0, o1;
    o0.x = accA[0]; o0.y = accA[1]; o0.z = accA[2]; o0.w = accA[3];
    o1.x = accA[4]; o1.y = accA[5]; o1.z = accA[6]; o1.w = accA[7];
    f4* Pp = reinterpret_cast<f4*>(P);
    __builtin_nontemporal_store(o0, &Pp[(size_t)n * 8 + 2 * l]);
    __builtin_nontemporal_store(o1, &Pp[(size_t)n * 8 + 2 * l + 1]);
  }
}

// Merge + fused next-layer GEMM (layers 1-2): A = relu(dinv*(PA+PB)+bias);
// G' = dinv .* (A @ Wn), fp16 out. Pure streaming, cheap.
__global__ __launch_bounds__(256) void k_mergemm(const float* __restrict__ Pbuf,
                                                 const float* __restrict__ dinv,
                                                 const float* __restrict__ bias,
                                                 const float* __restrict__ Wn,
                                                 _Float16* __restrict__ Gout) {
  __shared__ float Wl[HID * HID];    // 4 KB next-layer weights
  __shared__ float As[64][HID + 1];  // padded A rows
  int t = threadIdx.x;
  int l = t & 3;
  int slot = t >> 2;
  int n = blockIdx.x * 64 + slot;
  int nl = (n < NN) ? n : NN - 1;
#pragma unroll
  for (int q = 0; q < 4; q++) Wl[t + 256 * q] = Wn[t + 256 * q];

  const f4* PA = reinterpret_cast<const f4*>(Pbuf);
  const f4* PB = reinterpret_cast<const f4*>(Pbuf + (size_t)NN * HID);
  f4 a0 = NTL(&PA[(size_t)nl * 8 + 2 * l]);
  f4 a1 = NTL(&PA[(size_t)nl * 8 + 2 * l + 1]);
  f4 b0 = NTL(&PB[(size_t)nl * 8 + 2 * l]);
  f4 b1 = NTL(&PB[(size_t)nl * 8 + 2 * l + 1]);

  float s = dinv[nl];
  float4 bv0 = reinterpret_cast<const float4*>(bias)[2 * l];
  float4 bv1 = reinterpret_cast<const float4*>(bias)[2 * l + 1];
  As[slot][8 * l + 0] = fmaxf(s * (a0.x + b0.x) + bv0.x, 0.f);
  As[slot][8 * l + 1] = fmaxf(s * (a0.y + b0.y) + bv0.y, 0.f);
  As[slot][8 * l + 2] = fmaxf(s * (a0.z + b0.z) + bv0.z, 0.f);
  As[slot][8 * l + 3] = fmaxf(s * (a0.w + b0.w) + bv0.w, 0.f);
  As[slot][8 * l + 4] = fmaxf(s * (a1.x + b1.x) + bv1.x, 0.f);
  As[slot][8 * l + 5] = fmaxf(s * (a1.y + b1.y) + bv1.y, 0.f);
  As[slot][8 * l + 6] = fmaxf(s * (a1.z + b1.z) + bv1.z, 0.f);
  As[slot][8 * l + 7] = fmaxf(s * (a1.w + b1.w) + bv1.w, 0.f);
  __syncthreads();

  float o[8];
#pragma unroll
  for (int f = 0; f < 8; f++) o[f] = 0.f;
#pragma unroll
  for (int k = 0; k < HID; k++) {
    float a = As[slot][k];  // broadcast
#pragma unroll
    for (int f = 0; f < 8; f++) o[f] += a * Wl[k * HID + 8 * l + f];
  }
  if (n < NN) {
    h8 ov;
#pragma unroll
    for (int f = 0; f < 8; f++) ov[f] = (_Float16)(o[f] * s);
    reinterpret_cast<h8*>(Gout)[(size_t)n * 4 + l] = ov;
  }
}

// Final merge (layer 3): no relu, fp32 out for pool.
__global__ __launch_bounds__(256) void k_merge3(const float* __restrict__ Pbuf,
                                                const float* __restrict__ dinv,
                                                const float* __restrict__ bias,
                                                float* __restrict__ Xout) {
  int t = threadIdx.x;
  int l = t & 3;
  int slot = t >> 2;
  int n = blockIdx.x * 64 + slot;
  if (n >= NN) return;

  const f4* PA = reinterpret_cast<const f4*>(Pbuf);
  const f4* PB = reinterpret_cast<const f4*>(Pbuf + (size_t)NN * HID);
  f4 a0 = NTL(&PA[(size_t)n * 8 + 2 * l]);
  f4 a1 = NTL(&PA[(size_t)n * 8 + 2 * l + 1]);
  f4 b0 = NTL(&PB[(size_t)n * 8 + 2 * l]);
  f4 b1 = NTL(&PB[(size_t)n * 8 + 2 * l + 1]);

  float s = dinv[n];
  float4 bv0 = reinterpret_cast<const float4*>(bias)[2 * l];
  float4 bv1 = reinterpret_cast<const float4*>(bias)[2 * l + 1];
  float4 o0, o1;
  o0.x = s * (a0.x + b0.x) + bv0.x;
  o0.y = s * (a0.y + b0.y) + bv0.y;
  o0.z = s * (a0.z + b0.z) + bv0.z;
  o0.w = s * (a0.w + b0.w) + bv0.w;
  o1.x = s * (a1.x + b1.x) + bv1.x;
  o1.y = s * (a1.y + b1.y) + bv1.y;
  o1.z = s * (a1.z + b1.z) + bv1.z;
  o1.w = s * (a1.w + b1.w) + bv1.w;
  reinterpret_cast<float4*>(Xout)[(size_t)n * 8 + 2 * l] = o0;
  reinterpret_cast<float4*>(Xout)[(size_t)n * 8 + 2 * l + 1] = o1;
}

// Mean-pool: batch is sorted, so flush-on-graph-change keeps atomics rare.
__global__ __launch_bounds__(256) void k_pool(const float* __restrict__ X,
                                              const int* __restrict__ batch,
                                              float* __restrict__ sums,
                                              int* __restrict__ counts) {
  int t = threadIdx.x;
  int f = t & 31, slot = t >> 5;
  int base = blockIdx.x * 512;
  float acc = 0.f;
  int cnt = 0, cur = -1;
  for (int i = 0; i < 64; i++) {
    int n = base + slot + i * 8;
    if (n >= NN) break;
    int g = batch[n];
    if (g != cur) {
      if (cur >= 0) {
        atomicAdd(&sums[cur * HID + f], acc);
        if (f == 0) atomicAdd(&counts[cur], cnt);
      }
      cur = g;
      acc = 0.f;
      cnt = 0;
    }
    acc += X[(size_t)n * HID + f];
    cnt++;
  }
  if (cur >= 0) {
    atomicAdd(&sums[cur * HID + f], acc);
    if (f == 0) atomicAdd(&counts[cur], cnt);
  }
}

__global__ void k_fc(const float* __restrict__ sums, const int* __restrict__ counts,
                     const float* __restrict__ Wfc, const float* __restrict__ bfc,
                     float* __restrict__ out) {
  int idx = blockIdx.x * 256 + threadIdx.x;
  if (idx >= NGR * NC) return;
  int g = idx / NC, c = idx % NC;
  float inv = 1.f / fmaxf((float)counts[g], 1.f);
  float acc = bfc[c];
#pragma unroll
  for (int k = 0; k < HID; k++) acc += sums[g * HID + k] * inv * Wfc[k * NC + c];
  out[idx] = acc;
}

extern "C" void kernel_launch(void* const* d_in, const int* in_sizes, int n_in,
                              void* d_out, int out_size, void* d_ws, size_t ws_size,
                              hipStream_t stream) {
  (void)in_sizes; (void)n_in; (void)out_size; (void)ws_size;
  const float* x = (const float*)d_in[0];
  const int* ei = (const int*)d_in[1];
  const int* batch = (const int*)d_in[2];
  const float* W1 = (const float*)d_in[3];
  const float* b1 = (const float*)d_in[4];
  const float* W2 = (const float*)d_in[5];
  const float* b2 = (const float*)d_in[6];
  const float* W3 = (const float*)d_in[7];
  const float* b3 = (const float*)d_in[8];
  const float* Wfc = (const float*)d_in[9];
  const float* bfc = (const float*)d_in[10];
  float* out = (float*)d_out;

  char* ws = (char*)d_ws;
  size_t off = 0;
  auto alloc = [&](size_t bytes) -> void* {
    void* p = ws + off;
    off = (off + bytes + 255) & ~(size_t)255;
    return p;
  };
  float* dinv = (float*)alloc((size_t)NN * 4);
  int* row_ptr = (int*)alloc((size_t)(NN + 1) * 4);
  int* mid = (int*)alloc((size_t)NN * 4);
  int* bcur = (int*)alloc(NBUK * 4);
  int* col = (int*)alloc((size_t)EE * 4);
  // Union region: bpair (CSR build only) overlaps G1/G2/Abuf (layer phase).
  size_t bpair_bytes = (size_t)NBUK * BSLACK * 8;          // 27.4 MB
  size_t gbuf_bytes = (size_t)NN * HID * 2;                // 6.4 MB (fp16)
  size_t abuf_bytes = (size_t)NN * HID * 4;                // 12.8 MB (fp32)
  size_t need = 2 * gbuf_bytes + abuf_bytes;               // G1 + G2 + Abuf
  char* uni = (char*)alloc(bpair_bytes > need ? bpair_bytes : need);
  long long* bpair = (long long*)uni;
  _Float16* G1 = (_Float16*)uni;
  _Float16* G2b = (_Float16*)(uni + gbuf_bytes);
  float* Abuf = (float*)(uni + 2 * gbuf_bytes);
  float* Pbuf = (float*)alloc(2 * (size_t)NN * HID * 4);   // PA+PB 25.6 MB
  float* sums = (float*)alloc((size_t)NGR * HID * 4);
  int* counts = (int*)alloc((size_t)NGR * 4);

  hipMemsetAsync(sums, 0, (size_t)NGR * HID * 4, stream);
  hipMemsetAsync(counts, 0, (size_t)NGR * 4, stream);

  k_init<<<1, NBUK, 0, stream>>>(bcur);
  k_bucket<<<(EE + TILE - 1) / TILE, 1024, 0, stream>>>(ei, bcur, bpair);
  k_place<<<NBUK, 1024, 0, stream>>>(bpair, bcur, dinv, row_ptr, mid, col);

  k_gemm<FIN><<<(NN + 127) / 128, 256, 0, stream>>>(x, W1, dinv, G1);
  // Layer 1
  k_agghalf<<<AGH_GRID, 256, 0, stream>>>(G1, col, row_ptr, mid, Pbuf);
  k_mergemm<<<NGRP, 256, 0, stream>>>(Pbuf, dinv, b1, W2, G2b);
  // Layer 2 (reuse G1 buffer for G3)
  k_agghalf<<<AGH_GRID, 256, 0, stream>>>(G2b, col, row_ptr, mid, Pbuf);
  k_mergemm<<<NGRP, 256, 0, stream>>>(Pbuf, dinv, b2, W3, G1);
  // Layer 3
  k_agghalf<<<AGH_GRID, 256, 0, stream>>>(G1, col, row_ptr, mid, Pbuf);
  k_merge3<<<NGRP, 256, 0, stream>>>(Pbuf, dinv, b3, Abuf);

  k_pool<<<(NN + 511) / 512, 256, 0, stream>>>(Abuf, batch, sums, counts);
  k_fc<<<(NGR * NC + 255) / 256, 256, 0, stream>>>(sums, counts, Wfc, bfc, out);
}